// Round 1
// baseline (134.910 us; speedup 1.0000x reference)
//
#include <hip/hip_runtime.h>

typedef __attribute__((ext_vector_type(8))) _Float16 f16x8;
typedef __attribute__((ext_vector_type(4))) float f32x4;

#define KTOT 864      // padded K (847 used, zero-padded to 27*32)
#define FSTRIDE 872   // f16 elems per feature row in LDS (bank-stagger pad)
#define OSTRIDE 104   // f16 elems per out_act row in LDS (96 used)

// ---------------------------------------------------------------------------
// Precompute: fold softmax(merger_w) head-weights into W2/b2, producing the
// transposed f16 big matrix MatT[c][k] (64 x 864) and fc1BT[c][k] (64 x 96).
// Feature-row layout (k index):
//   ally : U rows kk*64+j (0..255), hsum 256..319, fsum 320..323
//   adv  : base 324: U 324..579, hsum 580..643, fsum 644..647
//   lm   : base 648: U 648..775, hsum 776..839, fsum 840..841
//   self : 842..845, const-1 (all biases) : 846, zero pad 847..863
// ---------------------------------------------------------------------------
__global__ __launch_bounds__(256) void precompute_kernel(
    const float* __restrict__ selfW, const float* __restrict__ selfB,
    const float* __restrict__ W2a, const float* __restrict__ b2a,
    const float* __restrict__ W2d, const float* __restrict__ b2d,
    const float* __restrict__ W2l, const float* __restrict__ b2l,
    const float* __restrict__ mergerW,
    const float* __restrict__ fc1W, const float* __restrict__ fc1b,
    _Float16* __restrict__ matT, _Float16* __restrict__ fc1BT)
{
  int g = blockIdx.x * 256 + threadIdx.x;
  if (g < 64 * KTOT) {
    int c = g / KTOT;
    int k = g - c * KTOT;
    // softmax over the 4 heads for channel c
    float v0 = mergerW[c], v1 = mergerW[64 + c], v2 = mergerW[128 + c], v3 = mergerW[192 + c];
    float mx = fmaxf(fmaxf(v0, v1), fmaxf(v2, v3));
    float e0 = expf(v0 - mx), e1 = expf(v1 - mx), e2 = expf(v2 - mx), e3 = expf(v3 - mx);
    float inv = 1.f / (e0 + e1 + e2 + e3);
    float w0 = e0 * inv, w1 = e1 * inv, w2 = e2 * inv, w3 = e3 * inv;
    auto HS = [&](const float* __restrict__ p, int base) -> float {
      return w0 * p[base + c] + w1 * p[base + 64 + c] + w2 * p[base + 128 + c] + w3 * p[base + 192 + c];
    };
    float val = 0.f;
    if (k < 256)      { int kk = k >> 6, j = k & 63;             val = HS(W2a, j * 1280 + kk * 256); }
    else if (k < 320) { int j = k - 256;                         val = HS(W2a, j * 1280 + 1024); }
    else if (k < 324) { int kk = k - 320;                        val = HS(b2a, kk * 256); }
    else if (k < 580) { int k2 = k - 324; int kk = k2 >> 6, j = k2 & 63; val = HS(W2d, j * 1280 + kk * 256); }
    else if (k < 644) { int j = k - 580;                         val = HS(W2d, j * 1280 + 1024); }
    else if (k < 648) { int kk = k - 644;                        val = HS(b2d, kk * 256); }
    else if (k < 776) { int k2 = k - 648; int kk = k2 >> 6, j = k2 & 63; val = HS(W2l, j * 768 + kk * 256); }
    else if (k < 840) { int j = k - 776;                         val = HS(W2l, j * 768 + 512); }
    else if (k < 842) { int kk = k - 840;                        val = HS(b2l, kk * 256); }
    else if (k < 846) {                                          val = selfW[(k - 842) * 64 + c]; }
    else if (k == 846){ val = 3.f * HS(b2a, 1024) + 2.f * HS(b2d, 1024) + 3.f * HS(b2l, 512) + selfB[c]; }
    matT[c * KTOT + k] = (_Float16)val;
  } else {
    int g2 = g - 64 * KTOT;   // grid sized so g2 < 64*96 exactly
    int c = g2 / 96;
    int k = g2 - c * 96;
    float val = 0.f;
    if (k < 66)       val = fc1W[k * 64 + c];   // k=64,65 are the action columns
    else if (k == 66) val = fc1b[c];            // bias via constant-1 feature
    fc1BT[c * 96 + k] = (_Float16)val;
  }
}

// ---------------------------------------------------------------------------
// Main kernel: 1 wave per block, 16 samples per wave. Phase 1 builds the 847
// features per sample into wave-private LDS (f16). Phase 2: 16x16x32 f16 MFMA
// over K=864 (A from LDS, B from L2-resident MatT). Epilogue: relu -> fc1
// MFMA (K=96) -> relu -> store x, fc2 via quad shuffle-reduce -> store q.
// No __syncthreads anywhere (all LDS is wave-private, DS ops in-order).
// ---------------------------------------------------------------------------
__global__ __launch_bounds__(64) void hpn_main(
    const float* __restrict__ inputs, const float* __restrict__ actions,
    const float* __restrict__ W1a, const float* __restrict__ B1a,
    const float* __restrict__ W1d, const float* __restrict__ B1d,
    const float* __restrict__ W1l, const float* __restrict__ B1l,
    const _Float16* __restrict__ matT, const _Float16* __restrict__ fc1BT,
    const float* __restrict__ fc2W, const float* __restrict__ fc2b,
    float* __restrict__ q_out, float* __restrict__ x_out)
{
  __shared__ __align__(16) _Float16 feats[16 * FSTRIDE];
  __shared__ __align__(16) _Float16 outact[16 * OSTRIDE];

  const int lane = threadIdx.x;
  const int base = blockIdx.x * 16;

  // per-lane hypernet-L1 columns (lane j holds column j of each W1)
  float w1a0 = W1a[lane], w1a1 = W1a[64 + lane], w1a2 = W1a[128 + lane], w1a3 = W1a[192 + lane];
  float vb1a = B1a[lane];
  float w1d0 = W1d[lane], w1d1 = W1d[64 + lane], w1d2 = W1d[128 + lane], w1d3 = W1d[192 + lane];
  float vb1d = B1d[lane];
  float w1l0 = W1l[lane], w1l1 = W1l[64 + lane];
  float vb1l = B1l[lane];

  // ---- Phase 1: features ----
  for (int i = 0; i < 16; ++i) {
    const float* orow = inputs + (base + i) * 30;   // wave-uniform -> scalar loads
    _Float16* fr = feats + i * FSTRIDE;

    // ally (3 entities, d=4)
    float Ua0 = 0, Ua1 = 0, Ua2 = 0, Ua3 = 0, hsa = 0;
#pragma unroll
    for (int n = 0; n < 3; ++n) {
      float f0 = orow[10 + 2 * n], f1 = orow[11 + 2 * n];
      float f2 = orow[20 + 2 * n], f3 = orow[21 + 2 * n];
      float t = fmaf(f0, w1a0, fmaf(f1, w1a1, fmaf(f2, w1a2, fmaf(f3, w1a3, vb1a))));
      float h = t > 0.f ? t : 0.01f * t;
      Ua0 = fmaf(h, f0, Ua0); Ua1 = fmaf(h, f1, Ua1);
      Ua2 = fmaf(h, f2, Ua2); Ua3 = fmaf(h, f3, Ua3); hsa += h;
    }
    fr[lane] = (_Float16)Ua0; fr[64 + lane] = (_Float16)Ua1;
    fr[128 + lane] = (_Float16)Ua2; fr[192 + lane] = (_Float16)Ua3;
    fr[256 + lane] = (_Float16)hsa;

    // adv (2 entities, d=4)
    float Ud0 = 0, Ud1 = 0, Ud2 = 0, Ud3 = 0, hsd = 0;
#pragma unroll
    for (int n = 0; n < 2; ++n) {
      float f0 = orow[16 + 2 * n], f1 = orow[17 + 2 * n];
      float f2 = orow[26 + 2 * n], f3 = orow[27 + 2 * n];
      float t = fmaf(f0, w1d0, fmaf(f1, w1d1, fmaf(f2, w1d2, fmaf(f3, w1d3, vb1d))));
      float h = t > 0.f ? t : 0.01f * t;
      Ud0 = fmaf(h, f0, Ud0); Ud1 = fmaf(h, f1, Ud1);
      Ud2 = fmaf(h, f2, Ud2); Ud3 = fmaf(h, f3, Ud3); hsd += h;
    }
    fr[324 + lane] = (_Float16)Ud0; fr[388 + lane] = (_Float16)Ud1;
    fr[452 + lane] = (_Float16)Ud2; fr[516 + lane] = (_Float16)Ud3;
    fr[580 + lane] = (_Float16)hsd;

    // landmarks (3 entities, d=2)
    float Ul0 = 0, Ul1 = 0, hsl = 0;
#pragma unroll
    for (int n = 0; n < 3; ++n) {
      float f0 = orow[4 + 2 * n], f1 = orow[5 + 2 * n];
      float t = fmaf(f0, w1l0, fmaf(f1, w1l1, vb1l));
      float h = t > 0.f ? t : 0.01f * t;
      Ul0 = fmaf(h, f0, Ul0); Ul1 = fmaf(h, f1, Ul1); hsl += h;
    }
    fr[648 + lane] = (_Float16)Ul0; fr[712 + lane] = (_Float16)Ul1;
    fr[776 + lane] = (_Float16)hsl;

    // specials: fsum / self / const-1 / zero pad (select by lane, no arrays)
    int k3 = lane & 3;
    float aw = (k3 == 0) ? (orow[10] + orow[12] + orow[14])
             : (k3 == 1) ? (orow[11] + orow[13] + orow[15])
             : (k3 == 2) ? (orow[20] + orow[22] + orow[24])
                         : (orow[21] + orow[23] + orow[25]);
    float dw = (k3 == 0) ? (orow[16] + orow[18])
             : (k3 == 1) ? (orow[17] + orow[19])
             : (k3 == 2) ? (orow[26] + orow[28])
                         : (orow[27] + orow[29]);
    float lw = ((lane & 1) == 0) ? (orow[4] + orow[6] + orow[8])
                                 : (orow[5] + orow[7] + orow[9]);
    int sk = (lane + 2) & 3;  // lanes 10..13 -> 0..3
    float sw = (sk == 0) ? orow[0] : (sk == 1) ? orow[1] : (sk == 2) ? orow[2] : orow[3];

    if (lane < 4)        fr[320 + lane] = (_Float16)aw;
    else if (lane < 8)   fr[640 + lane] = (_Float16)dw;   // 644..647
    else if (lane < 10)  fr[832 + lane] = (_Float16)lw;   // 840..841
    else if (lane < 14)  fr[832 + lane] = (_Float16)sw;   // 842..845
    else if (lane == 14) fr[846] = (_Float16)1.0f;
    else if (lane < 32)  fr[832 + lane] = (_Float16)0.0f; // 847..863
  }

  // ---- Phase 2: big GEMM, D(16x64) = F(16x864) @ M(864x64) ----
  const int m = lane & 15;      // A: row (sample), B/D: col (channel)
  const int quad = lane >> 4;   // k-subgroup
  f32x4 acc[4];
#pragma unroll
  for (int nt = 0; nt < 4; ++nt) acc[nt] = (f32x4){0.f, 0.f, 0.f, 0.f};

  const _Float16* aptr = feats + m * FSTRIDE + quad * 8;
  const _Float16* bptr = matT + m * KTOT + quad * 8;   // + nt*16*KTOT per col tile
#pragma unroll 3
  for (int kk = 0; kk < 27; ++kk) {
    f16x8 af = *(const f16x8*)(aptr + kk * 32);
#pragma unroll
    for (int nt = 0; nt < 4; ++nt) {
      f16x8 bf = *(const f16x8*)(bptr + nt * 16 * KTOT + kk * 32);
      acc[nt] = __builtin_amdgcn_mfma_f32_16x16x32_f16(af, bf, acc[nt], 0, 0, 0);
    }
  }

  // ---- Epilogue: out = relu(acc) -> LDS (f16), append actions + 1 + pad ----
#pragma unroll
  for (int nt = 0; nt < 4; ++nt)
#pragma unroll
    for (int i = 0; i < 4; ++i) {
      int r = quad * 4 + i;
      float v = fmaxf(acc[nt][i], 0.f);
      outact[r * OSTRIDE + nt * 16 + m] = (_Float16)v;
    }
  if (lane < 16) {
    int s = base + lane;
    _Float16* orp = outact + lane * OSTRIDE;
    orp[64] = (_Float16)actions[2 * s];
    orp[65] = (_Float16)actions[2 * s + 1];
    orp[66] = (_Float16)1.0f;
#pragma unroll
    for (int k = 67; k < 96; ++k) orp[k] = (_Float16)0.0f;
  }

  // ---- fc1: X(16x64) = relu( OA(16x96) @ fc1BT^T ) ----
  f32x4 xacc[4];
#pragma unroll
  for (int nt = 0; nt < 4; ++nt) xacc[nt] = (f32x4){0.f, 0.f, 0.f, 0.f};
  const _Float16* aptr2 = outact + m * OSTRIDE + quad * 8;
  const _Float16* cptr = fc1BT + m * 96 + quad * 8;
#pragma unroll
  for (int kk = 0; kk < 3; ++kk) {
    f16x8 af = *(const f16x8*)(aptr2 + kk * 32);
#pragma unroll
    for (int nt = 0; nt < 4; ++nt) {
      f16x8 bf = *(const f16x8*)(cptr + nt * 16 * 96 + kk * 32);
      xacc[nt] = __builtin_amdgcn_mfma_f32_16x16x32_f16(af, bf, xacc[nt], 0, 0, 0);
    }
  }

  // ---- store x, fc2 reduce -> q ----
  float wq0 = fc2W[m], wq1 = fc2W[16 + m], wq2 = fc2W[32 + m], wq3 = fc2W[48 + m];
  float qb = fc2b[0];
#pragma unroll
  for (int i = 0; i < 4; ++i) {
    int r = quad * 4 + i;
    int s = base + r;
    float x0 = fmaxf(xacc[0][i], 0.f);
    float x1 = fmaxf(xacc[1][i], 0.f);
    float x2 = fmaxf(xacc[2][i], 0.f);
    float x3 = fmaxf(xacc[3][i], 0.f);
    x_out[s * 64 + m]      = x0;
    x_out[s * 64 + 16 + m] = x1;
    x_out[s * 64 + 32 + m] = x2;
    x_out[s * 64 + 48 + m] = x3;
    float p = fmaf(x0, wq0, fmaf(x1, wq1, fmaf(x2, wq2, x3 * wq3)));
    p += __shfl_xor(p, 1, 64);
    p += __shfl_xor(p, 2, 64);
    p += __shfl_xor(p, 4, 64);
    p += __shfl_xor(p, 8, 64);
    if (m == 0) q_out[s] = p + qb;
  }
}

extern "C" void kernel_launch(void* const* d_in, const int* in_sizes, int n_in,
                              void* d_out, int out_size, void* d_ws, size_t ws_size,
                              hipStream_t stream) {
  const float* inputs  = (const float*)d_in[0];
  // d_in[1] = hidden_state (unused by the reference)
  const float* actions = (const float*)d_in[2];
  const float* selfW   = (const float*)d_in[3];
  const float* selfB   = (const float*)d_in[4];
  const float* W1a = (const float*)d_in[5],  *B1a = (const float*)d_in[6];
  const float* W2a = (const float*)d_in[7],  *b2a = (const float*)d_in[8];
  const float* W1d = (const float*)d_in[9],  *B1d = (const float*)d_in[10];
  const float* W2d = (const float*)d_in[11], *b2d = (const float*)d_in[12];
  const float* W1l = (const float*)d_in[13], *B1l = (const float*)d_in[14];
  const float* W2l = (const float*)d_in[15], *b2l = (const float*)d_in[16];
  const float* mergerW = (const float*)d_in[17];
  const float* fc1W = (const float*)d_in[18], *fc1b = (const float*)d_in[19];
  const float* fc2W = (const float*)d_in[20], *fc2b = (const float*)d_in[21];

  _Float16* matT  = (_Float16*)d_ws;            // 64*864 f16
  _Float16* fc1BT = matT + 64 * KTOT;           // 64*96 f16

  const int n = in_sizes[0] / 30;               // 16384
  precompute_kernel<<<240, 256, 0, stream>>>(selfW, selfB, W2a, b2a, W2d, b2d,
                                             W2l, b2l, mergerW, fc1W, fc1b,
                                             matT, fc1BT);
  float* q_out = (float*)d_out;
  float* x_out = q_out + n;
  hpn_main<<<n / 16, 64, 0, stream>>>(inputs, actions, W1a, B1a, W1d, B1d,
                                      W1l, B1l, matT, fc1BT, fc2W, fc2b,
                                      q_out, x_out);
}

// Round 2
// 124.343 us; speedup vs baseline: 1.0850x; 1.0850x over previous
//
#include <hip/hip_runtime.h>

typedef __attribute__((ext_vector_type(8))) _Float16 f16x8;
typedef __attribute__((ext_vector_type(4))) float f32x4;

#define KTOT 864      // padded K (847 used, zero-padded to 27*32)
#define FSTRIDE 872   // f16 elems per feature row in LDS (multiple of 8)
#define OSTRIDE 104   // f16 elems per out_act row in LDS (96 used)

// ---------------------------------------------------------------------------
// Precompute: fold softmax(merger_w) head-weights into W2/b2. Output is in
// MFMA *fragment order*: matB[((kk*4+nt)*64 + lane)*8 + j] holds the f16
// element (c = nt*16 + (lane&15), k = kk*32 + (lane>>4)*8 + j), so the main
// kernel's B loads are fully coalesced 1KB transactions. Same for fc1B.
// Logical (c,k) mapping of the big matrix:
//   ally : U rows kk*64+j (0..255), hsum 256..319, fsum 320..323
//   adv  : base 324: U 324..579, hsum 580..643, fsum 644..647
//   lm   : base 648: U 648..775, hsum 776..839, fsum 840..841
//   self : 842..845, const-1 (all biases) : 846, zero pad 847..863
// ---------------------------------------------------------------------------
__global__ __launch_bounds__(256) void precompute_kernel(
    const float* __restrict__ selfW, const float* __restrict__ selfB,
    const float* __restrict__ W2a, const float* __restrict__ b2a,
    const float* __restrict__ W2d, const float* __restrict__ b2d,
    const float* __restrict__ W2l, const float* __restrict__ b2l,
    const float* __restrict__ mergerW,
    const float* __restrict__ fc1W, const float* __restrict__ fc1b,
    _Float16* __restrict__ matB, _Float16* __restrict__ fc1B)
{
  int g = blockIdx.x * 256 + threadIdx.x;
  if (g < 64 * KTOT) {
    // fragment-order decode
    int j8 = g & 7;
    int l  = (g >> 3) & 63;
    int t  = g >> 9;            // 0..107 = kk*4+nt
    int nt = t & 3, kk = t >> 2;
    int c  = nt * 16 + (l & 15);
    int k  = kk * 32 + (l >> 4) * 8 + j8;

    // softmax over the 4 heads for channel c
    float v0 = mergerW[c], v1 = mergerW[64 + c], v2 = mergerW[128 + c], v3 = mergerW[192 + c];
    float mx = fmaxf(fmaxf(v0, v1), fmaxf(v2, v3));
    float e0 = expf(v0 - mx), e1 = expf(v1 - mx), e2 = expf(v2 - mx), e3 = expf(v3 - mx);
    float inv = 1.f / (e0 + e1 + e2 + e3);
    float w0 = e0 * inv, w1 = e1 * inv, w2 = e2 * inv, w3 = e3 * inv;
    auto HS = [&](const float* __restrict__ p, int base) -> float {
      return w0 * p[base + c] + w1 * p[base + 64 + c] + w2 * p[base + 128 + c] + w3 * p[base + 192 + c];
    };
    float val = 0.f;
    if (k < 256)      { int kkk = k >> 6, j = k & 63;             val = HS(W2a, j * 1280 + kkk * 256); }
    else if (k < 320) { int j = k - 256;                          val = HS(W2a, j * 1280 + 1024); }
    else if (k < 324) { int kkk = k - 320;                        val = HS(b2a, kkk * 256); }
    else if (k < 580) { int k2 = k - 324; int kkk = k2 >> 6, j = k2 & 63; val = HS(W2d, j * 1280 + kkk * 256); }
    else if (k < 644) { int j = k - 580;                          val = HS(W2d, j * 1280 + 1024); }
    else if (k < 648) { int kkk = k - 644;                        val = HS(b2d, kkk * 256); }
    else if (k < 776) { int k2 = k - 648; int kkk = k2 >> 6, j = k2 & 63; val = HS(W2l, j * 768 + kkk * 256); }
    else if (k < 840) { int j = k - 776;                          val = HS(W2l, j * 768 + 512); }
    else if (k < 842) { int kkk = k - 840;                        val = HS(b2l, kkk * 256); }
    else if (k < 846) {                                           val = selfW[(k - 842) * 64 + c]; }
    else if (k == 846){ val = 3.f * HS(b2a, 1024) + 2.f * HS(b2d, 1024) + 3.f * HS(b2l, 512) + selfB[c]; }
    matB[g] = (_Float16)val;
  } else {
    int g2 = g - 64 * KTOT;     // < 64*96, grid sized exactly
    int j8 = g2 & 7;
    int l  = (g2 >> 3) & 63;
    int t  = g2 >> 9;           // 0..11 = kk*4+nt
    int nt = t & 3, kk = t >> 2;
    int c  = nt * 16 + (l & 15);
    int k  = kk * 32 + (l >> 4) * 8 + j8;   // 0..95
    float val = 0.f;
    if (k < 66)       val = fc1W[k * 64 + c];   // k=64,65 are the action columns
    else if (k == 66) val = fc1b[c];            // bias via constant-1 feature
    fc1B[g2] = (_Float16)val;
  }
}

// ---------------------------------------------------------------------------
// Main kernel: 1 wave per block, 16 samples per wave.
//  Stage 0: one coalesced burst loads the wave's 16x30 inputs (+actions) to LDS.
//  Phase 1: build 847 features/sample into wave-private LDS (f16) from the
//           LDS stage (short-latency broadcasts instead of serial HBM reads).
//  Phase 2: 16x16x32 f16 MFMA over K=864; A from LDS, B = coalesced 1KB
//           fragment loads from L2-resident matB.
//  Epilogue: relu -> fc1 MFMA (K=96, fragment-ordered B) -> relu -> store x,
//           fc2 via quad shuffle-reduce -> store q.
// No __syncthreads anywhere (single wave; DS ops are in program order).
// ---------------------------------------------------------------------------
__global__ __launch_bounds__(64) void hpn_main(
    const float* __restrict__ inputs, const float* __restrict__ actions,
    const float* __restrict__ W1a, const float* __restrict__ B1a,
    const float* __restrict__ W1d, const float* __restrict__ B1d,
    const float* __restrict__ W1l, const float* __restrict__ B1l,
    const _Float16* __restrict__ matB, const _Float16* __restrict__ fc1B,
    const float* __restrict__ fc2W, const float* __restrict__ fc2b,
    float* __restrict__ q_out, float* __restrict__ x_out)
{
  __shared__ __align__(16) float   stage[16 * 32];        // 2 KB input stage
  __shared__ __align__(16) float   act[32];               // 16 samples x 2
  __shared__ __align__(16) _Float16 feats[16 * FSTRIDE];  // 27.9 KB
  __shared__ __align__(16) _Float16 outact[16 * OSTRIDE]; // 3.3 KB

  const int lane = threadIdx.x;
  const int base = blockIdx.x * 16;

  // ---- Stage 0: coalesced input burst (16 rows x 30 -> padded 32) ----
#pragma unroll
  for (int c = 0; c < 8; ++c) {
    int idx = lane + c * 64;            // 0..511
    int row = idx >> 5, col = idx & 31;
    stage[idx] = (col < 30) ? inputs[(base + row) * 30 + col] : 0.f;
  }
  if (lane < 32) act[lane] = actions[base * 2 + lane];

  // per-lane hypernet-L1 columns (lane j holds column j of each W1)
  float w1a0 = W1a[lane], w1a1 = W1a[64 + lane], w1a2 = W1a[128 + lane], w1a3 = W1a[192 + lane];
  float vb1a = B1a[lane];
  float w1d0 = W1d[lane], w1d1 = W1d[64 + lane], w1d2 = W1d[128 + lane], w1d3 = W1d[192 + lane];
  float vb1d = B1d[lane];
  float w1l0 = W1l[lane], w1l1 = W1l[64 + lane];
  float vb1l = B1l[lane];

  // ---- Phase 1: features ----
  for (int i = 0; i < 16; ++i) {
    float r[30];
#pragma unroll
    for (int e = 0; e < 30; ++e) r[e] = stage[i * 32 + e];  // ds_read_b128 merges
    _Float16* fr = feats + i * FSTRIDE;

    // ally (3 entities, d=4)
    float Ua0 = 0, Ua1 = 0, Ua2 = 0, Ua3 = 0, hsa = 0;
#pragma unroll
    for (int n = 0; n < 3; ++n) {
      float f0 = r[10 + 2 * n], f1 = r[11 + 2 * n];
      float f2 = r[20 + 2 * n], f3 = r[21 + 2 * n];
      float t = fmaf(f0, w1a0, fmaf(f1, w1a1, fmaf(f2, w1a2, fmaf(f3, w1a3, vb1a))));
      float h = t > 0.f ? t : 0.01f * t;
      Ua0 = fmaf(h, f0, Ua0); Ua1 = fmaf(h, f1, Ua1);
      Ua2 = fmaf(h, f2, Ua2); Ua3 = fmaf(h, f3, Ua3); hsa += h;
    }
    fr[lane] = (_Float16)Ua0; fr[64 + lane] = (_Float16)Ua1;
    fr[128 + lane] = (_Float16)Ua2; fr[192 + lane] = (_Float16)Ua3;
    fr[256 + lane] = (_Float16)hsa;

    // adv (2 entities, d=4)
    float Ud0 = 0, Ud1 = 0, Ud2 = 0, Ud3 = 0, hsd = 0;
#pragma unroll
    for (int n = 0; n < 2; ++n) {
      float f0 = r[16 + 2 * n], f1 = r[17 + 2 * n];
      float f2 = r[26 + 2 * n], f3 = r[27 + 2 * n];
      float t = fmaf(f0, w1d0, fmaf(f1, w1d1, fmaf(f2, w1d2, fmaf(f3, w1d3, vb1d))));
      float h = t > 0.f ? t : 0.01f * t;
      Ud0 = fmaf(h, f0, Ud0); Ud1 = fmaf(h, f1, Ud1);
      Ud2 = fmaf(h, f2, Ud2); Ud3 = fmaf(h, f3, Ud3); hsd += h;
    }
    fr[324 + lane] = (_Float16)Ud0; fr[388 + lane] = (_Float16)Ud1;
    fr[452 + lane] = (_Float16)Ud2; fr[516 + lane] = (_Float16)Ud3;
    fr[580 + lane] = (_Float16)hsd;

    // landmarks (3 entities, d=2)
    float Ul0 = 0, Ul1 = 0, hsl = 0;
#pragma unroll
    for (int n = 0; n < 3; ++n) {
      float f0 = r[4 + 2 * n], f1 = r[5 + 2 * n];
      float t = fmaf(f0, w1l0, fmaf(f1, w1l1, vb1l));
      float h = t > 0.f ? t : 0.01f * t;
      Ul0 = fmaf(h, f0, Ul0); Ul1 = fmaf(h, f1, Ul1); hsl += h;
    }
    fr[648 + lane] = (_Float16)Ul0; fr[712 + lane] = (_Float16)Ul1;
    fr[776 + lane] = (_Float16)hsl;

    // specials: fsum / self / const-1 / zero pad (select by lane)
    int k3 = lane & 3;
    float aw = (k3 == 0) ? (r[10] + r[12] + r[14])
             : (k3 == 1) ? (r[11] + r[13] + r[15])
             : (k3 == 2) ? (r[20] + r[22] + r[24])
                         : (r[21] + r[23] + r[25]);
    float dw = (k3 == 0) ? (r[16] + r[18])
             : (k3 == 1) ? (r[17] + r[19])
             : (k3 == 2) ? (r[26] + r[28])
                         : (r[27] + r[29]);
    float lw = ((lane & 1) == 0) ? (r[4] + r[6] + r[8])
                                 : (r[5] + r[7] + r[9]);
    int sk = (lane + 2) & 3;  // lanes 10..13 -> 0..3
    float sw = (sk == 0) ? r[0] : (sk == 1) ? r[1] : (sk == 2) ? r[2] : r[3];

    if (lane < 4)        fr[320 + lane] = (_Float16)aw;
    else if (lane < 8)   fr[640 + lane] = (_Float16)dw;   // 644..647
    else if (lane < 10)  fr[832 + lane] = (_Float16)lw;   // 840..841
    else if (lane < 14)  fr[832 + lane] = (_Float16)sw;   // 842..845
    else if (lane == 14) fr[846] = (_Float16)1.0f;
    else if (lane < 32)  fr[832 + lane] = (_Float16)0.0f; // 847..863
  }

  // ---- Phase 2: big GEMM, D(16x64) = F(16x864) @ M(864x64) ----
  const int m = lane & 15;      // A: row (sample), B/D: col (channel)
  const int quad = lane >> 4;   // k-subgroup
  f32x4 acc[4];
#pragma unroll
  for (int nt = 0; nt < 4; ++nt) acc[nt] = (f32x4){0.f, 0.f, 0.f, 0.f};

  const _Float16* aptr  = feats + m * FSTRIDE + quad * 8;
  const _Float16* bbase = matB + lane * 8;   // fragment-ordered: 1KB/instr, coalesced
#pragma unroll 3
  for (int kk = 0; kk < 27; ++kk) {
    f16x8 af = *(const f16x8*)(aptr + kk * 32);
#pragma unroll
    for (int nt = 0; nt < 4; ++nt) {
      f16x8 bf = *(const f16x8*)(bbase + (kk * 4 + nt) * 512);
      acc[nt] = __builtin_amdgcn_mfma_f32_16x16x32_f16(af, bf, acc[nt], 0, 0, 0);
    }
  }

  // ---- Epilogue: out = relu(acc) -> LDS (f16), append actions + 1 + pad ----
#pragma unroll
  for (int nt = 0; nt < 4; ++nt)
#pragma unroll
    for (int i = 0; i < 4; ++i) {
      int rrow = quad * 4 + i;
      float v = fmaxf(acc[nt][i], 0.f);
      outact[rrow * OSTRIDE + nt * 16 + m] = (_Float16)v;
    }
  if (lane < 16) {
    _Float16* orp = outact + lane * OSTRIDE;
    orp[64] = (_Float16)act[2 * lane];
    orp[65] = (_Float16)act[2 * lane + 1];
    orp[66] = (_Float16)1.0f;
#pragma unroll
    for (int k = 67; k < 96; ++k) orp[k] = (_Float16)0.0f;
  }

  // ---- fc1: X(16x64) = relu( OA(16x96) @ fc1B^T ) ----
  f32x4 xacc[4];
#pragma unroll
  for (int nt = 0; nt < 4; ++nt) xacc[nt] = (f32x4){0.f, 0.f, 0.f, 0.f};
  const _Float16* aptr2 = outact + m * OSTRIDE + quad * 8;
  const _Float16* cbase = fc1B + lane * 8;   // fragment-ordered
#pragma unroll
  for (int kk = 0; kk < 3; ++kk) {
    f16x8 af = *(const f16x8*)(aptr2 + kk * 32);
#pragma unroll
    for (int nt = 0; nt < 4; ++nt) {
      f16x8 bf = *(const f16x8*)(cbase + (kk * 4 + nt) * 512);
      xacc[nt] = __builtin_amdgcn_mfma_f32_16x16x32_f16(af, bf, xacc[nt], 0, 0, 0);
    }
  }

  // ---- store x, fc2 reduce -> q ----
  float wq0 = fc2W[m], wq1 = fc2W[16 + m], wq2 = fc2W[32 + m], wq3 = fc2W[48 + m];
  float qb = fc2b[0];
#pragma unroll
  for (int i = 0; i < 4; ++i) {
    int rrow = quad * 4 + i;
    int s = base + rrow;
    float x0 = fmaxf(xacc[0][i], 0.f);
    float x1 = fmaxf(xacc[1][i], 0.f);
    float x2 = fmaxf(xacc[2][i], 0.f);
    float x3 = fmaxf(xacc[3][i], 0.f);
    x_out[s * 64 + m]      = x0;   // 16 lanes -> one aligned 64B segment
    x_out[s * 64 + 16 + m] = x1;
    x_out[s * 64 + 32 + m] = x2;
    x_out[s * 64 + 48 + m] = x3;
    float p = fmaf(x0, wq0, fmaf(x1, wq1, fmaf(x2, wq2, x3 * wq3)));
    p += __shfl_xor(p, 1, 64);
    p += __shfl_xor(p, 2, 64);
    p += __shfl_xor(p, 4, 64);
    p += __shfl_xor(p, 8, 64);
    if (m == 0) q_out[s] = p + qb;
  }
}

extern "C" void kernel_launch(void* const* d_in, const int* in_sizes, int n_in,
                              void* d_out, int out_size, void* d_ws, size_t ws_size,
                              hipStream_t stream) {
  const float* inputs  = (const float*)d_in[0];
  // d_in[1] = hidden_state (unused by the reference)
  const float* actions = (const float*)d_in[2];
  const float* selfW   = (const float*)d_in[3];
  const float* selfB   = (const float*)d_in[4];
  const float* W1a = (const float*)d_in[5],  *B1a = (const float*)d_in[6];
  const float* W2a = (const float*)d_in[7],  *b2a = (const float*)d_in[8];
  const float* W1d = (const float*)d_in[9],  *B1d = (const float*)d_in[10];
  const float* W2d = (const float*)d_in[11], *b2d = (const float*)d_in[12];
  const float* W1l = (const float*)d_in[13], *B1l = (const float*)d_in[14];
  const float* W2l = (const float*)d_in[15], *b2l = (const float*)d_in[16];
  const float* mergerW = (const float*)d_in[17];
  const float* fc1W = (const float*)d_in[18], *fc1b = (const float*)d_in[19];
  const float* fc2W = (const float*)d_in[20], *fc2b = (const float*)d_in[21];

  _Float16* matB = (_Float16*)d_ws;             // 64*864 f16, fragment order
  _Float16* fc1B = matB + 64 * KTOT;            // 64*96 f16, fragment order

  const int n = in_sizes[0] / 30;               // 16384
  precompute_kernel<<<240, 256, 0, stream>>>(selfW, selfB, W2a, b2a, W2d, b2d,
                                             W2l, b2l, mergerW, fc1W, fc1b,
                                             matB, fc1B);
  float* q_out = (float*)d_out;
  float* x_out = q_out + n;
  hpn_main<<<n / 16, 64, 0, stream>>>(inputs, actions, W1a, B1a, W1d, B1d,
                                      W1l, B1l, matB, fc1B, fc2W, fc2b,
                                      q_out, x_out);
}

// Round 3
// 111.761 us; speedup vs baseline: 1.2071x; 1.1126x over previous
//
#include <hip/hip_runtime.h>

typedef __attribute__((ext_vector_type(8))) _Float16 f16x8;
typedef __attribute__((ext_vector_type(4))) float f32x4;

#define KTOT 864      // padded K (847 used, zero-padded to 27*32)
#define FSTRIDE 872   // f16 elems per feature row in LDS (multiple of 8)
#define OSTRIDE 104   // f16 elems per out_act row in LDS (96 used)

// ---------------------------------------------------------------------------
// Precompute: fold softmax(merger_w) head-weights into W2/b2. Output is in
// MFMA *fragment order*: matB[((kk*4+nt)*64 + lane)*8 + j] holds the f16
// element (c = nt*16 + (lane&15), k = kk*32 + (lane>>4)*8 + j), so the main
// kernel's B loads are fully coalesced 1KB transactions. Same for fc1B.
// Logical (c,k) mapping of the big matrix:
//   ally : U rows kk*64+j (0..255), hsum 256..319, fsum 320..323
//   adv  : base 324: U 324..579, hsum 580..643, fsum 644..647
//   lm   : base 648: U 648..775, hsum 776..839, fsum 840..841
//   self : 842..845, const-1 (all biases) : 846, zero pad 847..863
// ---------------------------------------------------------------------------
__global__ __launch_bounds__(256) void precompute_kernel(
    const float* __restrict__ selfW, const float* __restrict__ selfB,
    const float* __restrict__ W2a, const float* __restrict__ b2a,
    const float* __restrict__ W2d, const float* __restrict__ b2d,
    const float* __restrict__ W2l, const float* __restrict__ b2l,
    const float* __restrict__ mergerW,
    const float* __restrict__ fc1W, const float* __restrict__ fc1b,
    _Float16* __restrict__ matB, _Float16* __restrict__ fc1B)
{
  int g = blockIdx.x * 256 + threadIdx.x;
  if (g < 64 * KTOT) {
    // fragment-order decode
    int j8 = g & 7;
    int l  = (g >> 3) & 63;
    int t  = g >> 9;            // 0..107 = kk*4+nt
    int nt = t & 3, kk = t >> 2;
    int c  = nt * 16 + (l & 15);
    int k  = kk * 32 + (l >> 4) * 8 + j8;

    // softmax over the 4 heads for channel c
    float v0 = mergerW[c], v1 = mergerW[64 + c], v2 = mergerW[128 + c], v3 = mergerW[192 + c];
    float mx = fmaxf(fmaxf(v0, v1), fmaxf(v2, v3));
    float e0 = expf(v0 - mx), e1 = expf(v1 - mx), e2 = expf(v2 - mx), e3 = expf(v3 - mx);
    float inv = 1.f / (e0 + e1 + e2 + e3);
    float w0 = e0 * inv, w1 = e1 * inv, w2 = e2 * inv, w3 = e3 * inv;
    auto HS = [&](const float* __restrict__ p, int base) -> float {
      return w0 * p[base + c] + w1 * p[base + 64 + c] + w2 * p[base + 128 + c] + w3 * p[base + 192 + c];
    };
    float val = 0.f;
    if (k < 256)      { int kkk = k >> 6, j = k & 63;             val = HS(W2a, j * 1280 + kkk * 256); }
    else if (k < 320) { int j = k - 256;                          val = HS(W2a, j * 1280 + 1024); }
    else if (k < 324) { int kkk = k - 320;                        val = HS(b2a, kkk * 256); }
    else if (k < 580) { int k2 = k - 324; int kkk = k2 >> 6, j = k2 & 63; val = HS(W2d, j * 1280 + kkk * 256); }
    else if (k < 644) { int j = k - 580;                          val = HS(W2d, j * 1280 + 1024); }
    else if (k < 648) { int kkk = k - 644;                        val = HS(b2d, kkk * 256); }
    else if (k < 776) { int k2 = k - 648; int kkk = k2 >> 6, j = k2 & 63; val = HS(W2l, j * 768 + kkk * 256); }
    else if (k < 840) { int j = k - 776;                          val = HS(W2l, j * 768 + 512); }
    else if (k < 842) { int kkk = k - 840;                        val = HS(b2l, kkk * 256); }
    else if (k < 846) {                                           val = selfW[(k - 842) * 64 + c]; }
    else if (k == 846){ val = 3.f * HS(b2a, 1024) + 2.f * HS(b2d, 1024) + 3.f * HS(b2l, 512) + selfB[c]; }
    matB[g] = (_Float16)val;
  } else {
    int g2 = g - 64 * KTOT;     // < 64*96, grid sized exactly
    int j8 = g2 & 7;
    int l  = (g2 >> 3) & 63;
    int t  = g2 >> 9;           // 0..11 = kk*4+nt
    int nt = t & 3, kk = t >> 2;
    int c  = nt * 16 + (l & 15);
    int k  = kk * 32 + (l >> 4) * 8 + j8;   // 0..95
    float val = 0.f;
    if (k < 66)       val = fc1W[k * 64 + c];   // k=64,65 are the action columns
    else if (k == 66) val = fc1b[c];            // bias via constant-1 feature
    fc1B[g2] = (_Float16)val;
  }
}

// ---------------------------------------------------------------------------
// Main kernel: 1 wave per block, 16 samples per wave. All long-latency loads
// (inputs burst, W1 columns, kk=0 B-fragments, all fc1B fragments, fc2W/b,
// actions) are issued at the TOP so they ride out phase-1 compute latency
// (only 1 wave/SIMD -> ILP is the only latency hiding available).
//  Phase 1: entity features -> wave-private LDS (f16); specials hoisted to a
//           single 4-iter 64-lane pass (was a 35-instr tail x16 iters).
//  Phase 2: 16x16x32 f16 MFMA over K=864; A from LDS, B = coalesced 1KB
//           fragment loads from L2-resident matB.
//  Epilogue: relu -> fc1 MFMA (K=96, preloaded fragments) -> relu -> store x,
//           fc2 via quad shuffle-reduce -> store q.
// No __syncthreads anywhere (single wave; DS ops are in program order).
// ---------------------------------------------------------------------------
__global__ __launch_bounds__(64) void hpn_main(
    const float* __restrict__ inputs, const float* __restrict__ actions,
    const float* __restrict__ W1a, const float* __restrict__ B1a,
    const float* __restrict__ W1d, const float* __restrict__ B1d,
    const float* __restrict__ W1l, const float* __restrict__ B1l,
    const _Float16* __restrict__ matB, const _Float16* __restrict__ fc1B,
    const float* __restrict__ fc2W, const float* __restrict__ fc2b,
    float* __restrict__ q_out, float* __restrict__ x_out)
{
  __shared__ __align__(16) float   stage[16 * 32];        // 2 KB input stage
  __shared__ __align__(16) _Float16 feats[16 * FSTRIDE];  // 27.9 KB
  __shared__ __align__(16) _Float16 outact[16 * OSTRIDE]; // 3.3 KB

  const int lane = threadIdx.x;
  const int base = blockIdx.x * 16;
  const int m = lane & 15;      // MFMA: A row (sample) / B,D col (channel)
  const int quad = lane >> 4;   // MFMA k-subgroup

  // ---- issue ALL long-latency loads up front ----
  float sbuf[8];
#pragma unroll
  for (int c = 0; c < 8; ++c) {
    int idx = lane + c * 64;            // 0..511
    int row = idx >> 5, col = idx & 31;
    sbuf[c] = (col < 30) ? inputs[(base + row) * 30 + col] : 0.f;
  }
  float a0 = 0.f, a1 = 0.f;
  if (lane < 16) { a0 = actions[base * 2 + 2 * lane]; a1 = actions[base * 2 + 2 * lane + 1]; }

  float w1a0 = W1a[lane], w1a1 = W1a[64 + lane], w1a2 = W1a[128 + lane], w1a3 = W1a[192 + lane];
  float vb1a = B1a[lane];
  float w1d0 = W1d[lane], w1d1 = W1d[64 + lane], w1d2 = W1d[128 + lane], w1d3 = W1d[192 + lane];
  float vb1d = B1d[lane];
  float w1l0 = W1l[lane], w1l1 = W1l[64 + lane];
  float vb1l = B1l[lane];

  float wq0 = fc2W[m], wq1 = fc2W[16 + m], wq2 = fc2W[32 + m], wq3 = fc2W[48 + m];
  float qb = fc2b[0];

  const _Float16* bbase = matB + lane * 8;   // fragment-ordered: 1KB/instr
  f16x8 b0 = *(const f16x8*)(bbase);
  f16x8 b1 = *(const f16x8*)(bbase + 512);
  f16x8 b2 = *(const f16x8*)(bbase + 1024);
  f16x8 b3 = *(const f16x8*)(bbase + 1536);

  const _Float16* cbase = fc1B + lane * 8;   // fragment-ordered fc1 B
  f16x8 cfrag[12];
#pragma unroll
  for (int t = 0; t < 12; ++t) cfrag[t] = *(const f16x8*)(cbase + t * 512);

  // ---- stage inputs to LDS; bulk-zero pad regions ----
#pragma unroll
  for (int c = 0; c < 8; ++c) stage[lane + c * 64] = sbuf[c];
#pragma unroll
  for (int p = 0; p < 4; ++p) {          // feats cols 832..863 := 0 (pad zone)
    int idx = p * 64 + lane;
    int row = idx >> 4, d = idx & 15;
    *(float*)(feats + row * FSTRIDE + 832 + d * 2) = 0.f;
  }
#pragma unroll
  for (int p = 0; p < 4; ++p) {          // outact cols 64..95 := 0
    int idx = p * 64 + lane;
    int row = idx >> 4, d = idx & 15;
    *(float*)(outact + row * OSTRIDE + 64 + d * 2) = 0.f;
  }

  // ---- Phase 1: entity features (specials hoisted out) ----
  for (int i = 0; i < 16; ++i) {
    float r[30];
#pragma unroll
    for (int e = 0; e < 30; ++e) r[e] = stage[i * 32 + e];  // ds_read_b128 merges
    _Float16* fr = feats + i * FSTRIDE;

    // ally (3 entities, d=4)
    float Ua0 = 0, Ua1 = 0, Ua2 = 0, Ua3 = 0, hsa = 0;
#pragma unroll
    for (int n = 0; n < 3; ++n) {
      float f0 = r[10 + 2 * n], f1 = r[11 + 2 * n];
      float f2 = r[20 + 2 * n], f3 = r[21 + 2 * n];
      float t = fmaf(f0, w1a0, fmaf(f1, w1a1, fmaf(f2, w1a2, fmaf(f3, w1a3, vb1a))));
      float h = t > 0.f ? t : 0.01f * t;
      Ua0 = fmaf(h, f0, Ua0); Ua1 = fmaf(h, f1, Ua1);
      Ua2 = fmaf(h, f2, Ua2); Ua3 = fmaf(h, f3, Ua3); hsa += h;
    }
    fr[lane] = (_Float16)Ua0; fr[64 + lane] = (_Float16)Ua1;
    fr[128 + lane] = (_Float16)Ua2; fr[192 + lane] = (_Float16)Ua3;
    fr[256 + lane] = (_Float16)hsa;

    // adv (2 entities, d=4)
    float Ud0 = 0, Ud1 = 0, Ud2 = 0, Ud3 = 0, hsd = 0;
#pragma unroll
    for (int n = 0; n < 2; ++n) {
      float f0 = r[16 + 2 * n], f1 = r[17 + 2 * n];
      float f2 = r[26 + 2 * n], f3 = r[27 + 2 * n];
      float t = fmaf(f0, w1d0, fmaf(f1, w1d1, fmaf(f2, w1d2, fmaf(f3, w1d3, vb1d))));
      float h = t > 0.f ? t : 0.01f * t;
      Ud0 = fmaf(h, f0, Ud0); Ud1 = fmaf(h, f1, Ud1);
      Ud2 = fmaf(h, f2, Ud2); Ud3 = fmaf(h, f3, Ud3); hsd += h;
    }
    fr[324 + lane] = (_Float16)Ud0; fr[388 + lane] = (_Float16)Ud1;
    fr[452 + lane] = (_Float16)Ud2; fr[516 + lane] = (_Float16)Ud3;
    fr[580 + lane] = (_Float16)hsd;

    // landmarks (3 entities, d=2)
    float Ul0 = 0, Ul1 = 0, hsl = 0;
#pragma unroll
    for (int n = 0; n < 3; ++n) {
      float f0 = r[4 + 2 * n], f1 = r[5 + 2 * n];
      float t = fmaf(f0, w1l0, fmaf(f1, w1l1, vb1l));
      float h = t > 0.f ? t : 0.01f * t;
      Ul0 = fmaf(h, f0, Ul0); Ul1 = fmaf(h, f1, Ul1); hsl += h;
    }
    fr[648 + lane] = (_Float16)Ul0; fr[712 + lane] = (_Float16)Ul1;
    fr[776 + lane] = (_Float16)hsl;
  }

  // ---- specials pass: 16 samples x 16 slots over 4 x 64 lanes ----
#pragma unroll
  for (int p = 0; p < 4; ++p) {
    int idx = p * 64 + lane;
    int i = idx >> 4, t = idx & 15;
    const float* rs = stage + i * 32;
    float val;
    if (t < 4)       { int b = ((t < 2) ? 10 : 20) + (t & 1); val = rs[b] + rs[b + 2] + rs[b + 4]; }
    else if (t < 8)  { int b = ((t < 6) ? 16 : 26) + (t & 1); val = rs[b] + rs[b + 2]; }
    else if (t < 10) { int b = 4 + (t & 1);                   val = rs[b] + rs[b + 2] + rs[b + 4]; }
    else if (t < 14) {                                        val = rs[t - 10]; }
    else if (t == 14){                                        val = 1.0f; }
    else             {                                        val = 0.0f; }
    int k = (t < 4) ? 320 + t : (t < 8) ? 640 + t : (t < 15) ? 832 + t : 863;
    feats[i * FSTRIDE + k] = (_Float16)val;
  }

  // ---- Phase 2: big GEMM, D(16x64) = F(16x864) @ M(864x64) ----
  f32x4 acc[4];
#pragma unroll
  for (int nt = 0; nt < 4; ++nt) acc[nt] = (f32x4){0.f, 0.f, 0.f, 0.f};

  const _Float16* aptr = feats + m * FSTRIDE + quad * 8;
  {
    f16x8 af = *(const f16x8*)(aptr);
    acc[0] = __builtin_amdgcn_mfma_f32_16x16x32_f16(af, b0, acc[0], 0, 0, 0);
    acc[1] = __builtin_amdgcn_mfma_f32_16x16x32_f16(af, b1, acc[1], 0, 0, 0);
    acc[2] = __builtin_amdgcn_mfma_f32_16x16x32_f16(af, b2, acc[2], 0, 0, 0);
    acc[3] = __builtin_amdgcn_mfma_f32_16x16x32_f16(af, b3, acc[3], 0, 0, 0);
  }
#pragma unroll 3
  for (int kk = 1; kk < 27; ++kk) {
    f16x8 af = *(const f16x8*)(aptr + kk * 32);
#pragma unroll
    for (int nt = 0; nt < 4; ++nt) {
      f16x8 bf = *(const f16x8*)(bbase + (kk * 4 + nt) * 512);
      acc[nt] = __builtin_amdgcn_mfma_f32_16x16x32_f16(af, bf, acc[nt], 0, 0, 0);
    }
  }

  // ---- Epilogue: out = relu(acc) -> LDS (f16), append actions + 1 ----
#pragma unroll
  for (int nt = 0; nt < 4; ++nt)
#pragma unroll
    for (int i = 0; i < 4; ++i) {
      int rrow = quad * 4 + i;
      float v = fmaxf(acc[nt][i], 0.f);
      outact[rrow * OSTRIDE + nt * 16 + m] = (_Float16)v;
    }
  if (lane < 16) {
    _Float16* orp = outact + lane * OSTRIDE;
    orp[64] = (_Float16)a0;
    orp[65] = (_Float16)a1;
    orp[66] = (_Float16)1.0f;
  }

  // ---- fc1: X(16x64) = relu( OA(16x96) @ fc1B^T ) ----
  f32x4 xacc[4];
#pragma unroll
  for (int nt = 0; nt < 4; ++nt) xacc[nt] = (f32x4){0.f, 0.f, 0.f, 0.f};
  const _Float16* aptr2 = outact + m * OSTRIDE + quad * 8;
#pragma unroll
  for (int kk = 0; kk < 3; ++kk) {
    f16x8 af = *(const f16x8*)(aptr2 + kk * 32);
#pragma unroll
    for (int nt = 0; nt < 4; ++nt)
      xacc[nt] = __builtin_amdgcn_mfma_f32_16x16x32_f16(af, cfrag[kk * 4 + nt], xacc[nt], 0, 0, 0);
  }

  // ---- store x, fc2 reduce -> q ----
#pragma unroll
  for (int i = 0; i < 4; ++i) {
    int rrow = quad * 4 + i;
    int s = base + rrow;
    float x0 = fmaxf(xacc[0][i], 0.f);
    float x1 = fmaxf(xacc[1][i], 0.f);
    float x2 = fmaxf(xacc[2][i], 0.f);
    float x3 = fmaxf(xacc[3][i], 0.f);
    x_out[s * 64 + m]      = x0;   // 16 lanes -> one aligned 64B segment
    x_out[s * 64 + 16 + m] = x1;
    x_out[s * 64 + 32 + m] = x2;
    x_out[s * 64 + 48 + m] = x3;
    float p = fmaf(x0, wq0, fmaf(x1, wq1, fmaf(x2, wq2, x3 * wq3)));
    p += __shfl_xor(p, 1, 64);
    p += __shfl_xor(p, 2, 64);
    p += __shfl_xor(p, 4, 64);
    p += __shfl_xor(p, 8, 64);
    if (m == 0) q_out[s] = p + qb;
  }
}

extern "C" void kernel_launch(void* const* d_in, const int* in_sizes, int n_in,
                              void* d_out, int out_size, void* d_ws, size_t ws_size,
                              hipStream_t stream) {
  const float* inputs  = (const float*)d_in[0];
  // d_in[1] = hidden_state (unused by the reference)
  const float* actions = (const float*)d_in[2];
  const float* selfW   = (const float*)d_in[3];
  const float* selfB   = (const float*)d_in[4];
  const float* W1a = (const float*)d_in[5],  *B1a = (const float*)d_in[6];
  const float* W2a = (const float*)d_in[7],  *b2a = (const float*)d_in[8];
  const float* W1d = (const float*)d_in[9],  *B1d = (const float*)d_in[10];
  const float* W2d = (const float*)d_in[11], *b2d = (const float*)d_in[12];
  const float* W1l = (const float*)d_in[13], *B1l = (const float*)d_in[14];
  const float* W2l = (const float*)d_in[15], *b2l = (const float*)d_in[16];
  const float* mergerW = (const float*)d_in[17];
  const float* fc1W = (const float*)d_in[18], *fc1b = (const float*)d_in[19];
  const float* fc2W = (const float*)d_in[20], *fc2b = (const float*)d_in[21];

  _Float16* matB = (_Float16*)d_ws;             // 64*864 f16, fragment order
  _Float16* fc1B = matB + 64 * KTOT;            // 64*96 f16, fragment order

  const int n = in_sizes[0] / 30;               // 16384
  precompute_kernel<<<240, 256, 0, stream>>>(selfW, selfB, W2a, b2a, W2d, b2d,
                                             W2l, b2l, mergerW, fc1W, fc1b,
                                             matB, fc1B);
  float* q_out = (float*)d_out;
  float* x_out = q_out + n;
  hpn_main<<<n / 16, 64, 0, stream>>>(inputs, actions, W1a, B1a, W1d, B1d,
                                      W1l, B1l, matB, fc1B, fc2W, fc2b,
                                      q_out, x_out);
}

// Round 4
// 109.115 us; speedup vs baseline: 1.2364x; 1.0242x over previous
//
#include <hip/hip_runtime.h>

typedef __attribute__((ext_vector_type(8))) _Float16 f16x8;
typedef __attribute__((ext_vector_type(4))) float f32x4;

#define KTOT 864      // padded K (847 used, zero-padded to 27*32)
#define FSTRIDE 872   // f16 elems per feature row in LDS (multiple of 8)
#define OSTRIDE 104   // f16 elems per out_act row in LDS (96 used)

// ---------------------------------------------------------------------------
// Precompute: fold softmax(merger_w) head-weights into W2/b2. Output is in
// MFMA *fragment order*: matB[((kk*4+nt)*64 + lane)*8 + j] holds the f16
// element (c = nt*16 + (lane&15), k = kk*32 + (lane>>4)*8 + j). Same for fc1B.
// Logical (c,k) map (j-major U packing so the main kernel's feature writes
// are contiguous per lane):
//   ally : U k=4j+kk (0..255), hsum 256..319, fsum 320..323
//   adv  : base 324: U 324+4j+kk (..579), hsum 580..643, fsum 644..647
//   lm   : base 648: U 648+2j+kk (..775), hsum 776..839, fsum 840..841
//   self : 842..845, const-1 (all biases) : 846, zero pad 847..863
// ---------------------------------------------------------------------------
__global__ __launch_bounds__(256) void precompute_kernel(
    const float* __restrict__ selfW, const float* __restrict__ selfB,
    const float* __restrict__ W2a, const float* __restrict__ b2a,
    const float* __restrict__ W2d, const float* __restrict__ b2d,
    const float* __restrict__ W2l, const float* __restrict__ b2l,
    const float* __restrict__ mergerW,
    const float* __restrict__ fc1W, const float* __restrict__ fc1b,
    _Float16* __restrict__ matB, _Float16* __restrict__ fc1B)
{
  int g = blockIdx.x * 256 + threadIdx.x;
  if (g < 64 * KTOT) {
    // fragment-order decode
    int j8 = g & 7;
    int l  = (g >> 3) & 63;
    int t  = g >> 9;            // 0..107 = kk*4+nt
    int nt = t & 3, kk = t >> 2;
    int c  = nt * 16 + (l & 15);
    int k  = kk * 32 + (l >> 4) * 8 + j8;

    // softmax over the 4 heads for channel c
    float v0 = mergerW[c], v1 = mergerW[64 + c], v2 = mergerW[128 + c], v3 = mergerW[192 + c];
    float mx = fmaxf(fmaxf(v0, v1), fmaxf(v2, v3));
    float e0 = expf(v0 - mx), e1 = expf(v1 - mx), e2 = expf(v2 - mx), e3 = expf(v3 - mx);
    float inv = 1.f / (e0 + e1 + e2 + e3);
    float w0 = e0 * inv, w1 = e1 * inv, w2 = e2 * inv, w3 = e3 * inv;
    auto HS = [&](const float* __restrict__ p, int base) -> float {
      return w0 * p[base + c] + w1 * p[base + 64 + c] + w2 * p[base + 128 + c] + w3 * p[base + 192 + c];
    };
    float val = 0.f;
    if (k < 256)      { int j = k >> 2, kkk = k & 3;              val = HS(W2a, j * 1280 + kkk * 256); }
    else if (k < 320) { int j = k - 256;                          val = HS(W2a, j * 1280 + 1024); }
    else if (k < 324) { int kkk = k - 320;                        val = HS(b2a, kkk * 256); }
    else if (k < 580) { int k2 = k - 324; int j = k2 >> 2, kkk = k2 & 3; val = HS(W2d, j * 1280 + kkk * 256); }
    else if (k < 644) { int j = k - 580;                          val = HS(W2d, j * 1280 + 1024); }
    else if (k < 648) { int kkk = k - 644;                        val = HS(b2d, kkk * 256); }
    else if (k < 776) { int k2 = k - 648; int j = k2 >> 1, kkk = k2 & 1; val = HS(W2l, j * 768 + kkk * 256); }
    else if (k < 840) { int j = k - 776;                          val = HS(W2l, j * 768 + 512); }
    else if (k < 842) { int kkk = k - 840;                        val = HS(b2l, kkk * 256); }
    else if (k < 846) {                                           val = selfW[(k - 842) * 64 + c]; }
    else if (k == 846){ val = 3.f * HS(b2a, 1024) + 2.f * HS(b2d, 1024) + 3.f * HS(b2l, 512) + selfB[c]; }
    matB[g] = (_Float16)val;
  } else {
    int g2 = g - 64 * KTOT;     // < 64*96, grid sized exactly
    int j8 = g2 & 7;
    int l  = (g2 >> 3) & 63;
    int t  = g2 >> 9;           // 0..11 = kk*4+nt
    int nt = t & 3, kk = t >> 2;
    int c  = nt * 16 + (l & 15);
    int k  = kk * 32 + (l >> 4) * 8 + j8;   // 0..95
    float val = 0.f;
    if (k < 66)       val = fc1W[k * 64 + c];   // k=64,65 are the action columns
    else if (k == 66) val = fc1b[c];            // bias via constant-1 feature
    fc1B[g2] = (_Float16)val;
  }
}

// ---------------------------------------------------------------------------
// Main kernel: 2 waves per block, 16 samples per block (K-split cooperation).
//  - wave w builds features for samples 8w..8w+7 (wave-private writes),
//  - barrier,
//  - wave w runs MFMA over K-tiles [13w, 13w+13+w) (wave0:13, wave1:14),
//  - wave1 dumps partial acc to LDS, barrier, exits; wave0 combines and runs
//    the epilogue (relu -> fc1 MFMA -> relu -> store x, fc2 reduce -> q).
// 2048 waves total = 2 waves/SIMD (vs 1 before) with unchanged B traffic.
// Feature U-blocks are j-major so each lane writes contiguous packed f16
// (cvt_pkrtz + ds_write_b64) instead of 13 scattered b16 stores.
// ---------------------------------------------------------------------------
__global__ __launch_bounds__(128) void hpn_main(
    const float* __restrict__ inputs, const float* __restrict__ actions,
    const float* __restrict__ W1a, const float* __restrict__ B1a,
    const float* __restrict__ W1d, const float* __restrict__ B1d,
    const float* __restrict__ W1l, const float* __restrict__ B1l,
    const _Float16* __restrict__ matB, const _Float16* __restrict__ fc1B,
    const float* __restrict__ fc2W, const float* __restrict__ fc2b,
    float* __restrict__ q_out, float* __restrict__ x_out)
{
  __shared__ __align__(16) float    stage[16 * 32];        // 2 KB input stage
  __shared__ __align__(16) _Float16 feats[16 * FSTRIDE];   // 27.9 KB
  __shared__ __align__(16) _Float16 outact[16 * OSTRIDE];  // 3.3 KB
  __shared__ __align__(16) float    partial[64 * 16];      // 4 KB wave1 acc

  const int tid  = threadIdx.x;
  const int lane = tid & 63;
  const int wave = tid >> 6;
  const int base = blockIdx.x * 16;
  const int m = lane & 15;      // MFMA: A row (sample) / B,D col (channel)
  const int quad = lane >> 4;   // MFMA k-subgroup

  // ---- issue long-latency loads up front ----
  float sbuf[4];
#pragma unroll
  for (int c = 0; c < 4; ++c) {      // each wave stages its OWN 8 samples
    int idx = lane + c * 64;         // 0..255
    int row = wave * 8 + (idx >> 5), col = idx & 31;
    sbuf[c] = (col < 30) ? inputs[(base + row) * 30 + col] : 0.f;
  }
  float a0 = 0.f, a1 = 0.f;
  if (tid < 16) { a0 = actions[base * 2 + 2 * tid]; a1 = actions[base * 2 + 2 * tid + 1]; }

  float w1a0 = W1a[lane], w1a1 = W1a[64 + lane], w1a2 = W1a[128 + lane], w1a3 = W1a[192 + lane];
  float vb1a = B1a[lane];
  float w1d0 = W1d[lane], w1d1 = W1d[64 + lane], w1d2 = W1d[128 + lane], w1d3 = W1d[192 + lane];
  float vb1d = B1d[lane];
  float w1l0 = W1l[lane], w1l1 = W1l[64 + lane];
  float vb1l = B1l[lane];

  float wq0 = fc2W[m], wq1 = fc2W[16 + m], wq2 = fc2W[32 + m], wq3 = fc2W[48 + m];
  float qb = fc2b[0];

  const _Float16* bbase = matB + lane * 8;   // fragment-ordered: 1KB/instr
  const int kk0 = wave * 13;                 // wave0: tiles 0..12, wave1: 13..26
  f16x8 bp[4];
#pragma unroll
  for (int nt = 0; nt < 4; ++nt) bp[nt] = *(const f16x8*)(bbase + (kk0 * 4 + nt) * 512);

  // ---- stage inputs to LDS (own rows); bulk-zero pad regions ----
#pragma unroll
  for (int c = 0; c < 4; ++c) {
    int idx = lane + c * 64;
    int row = wave * 8 + (idx >> 5), col = idx & 31;
    stage[row * 32 + col] = sbuf[c];
  }
#pragma unroll
  for (int p = 0; p < 2; ++p) {          // feats cols 832..863 := 0 (own rows)
    int idx = p * 64 + lane;             // 0..127 -> 8 rows x 16 dwords
    int row = wave * 8 + (idx >> 4), d = idx & 15;
    *(float*)(feats + row * FSTRIDE + 832 + d * 2) = 0.f;
  }
#pragma unroll
  for (int p = 0; p < 2; ++p) {          // outact cols 64..95 := 0 (split 128 thr)
    int idx = p * 128 + tid;             // 0..255 -> 16 rows x 16 dwords
    int row = idx >> 4, d = idx & 15;
    *(float*)(outact + row * OSTRIDE + 64 + d * 2) = 0.f;
  }

  // ---- Phase 1: entity features for this wave's 8 samples ----
  for (int ii = 0; ii < 8; ++ii) {
    int i = wave * 8 + ii;
    float r[30];
#pragma unroll
    for (int e = 0; e < 30; ++e) r[e] = stage[i * 32 + e];  // ds_read_b128 merges
    _Float16* fr = feats + i * FSTRIDE;

    // ally (3 entities, d=4)
    float Ua0 = 0, Ua1 = 0, Ua2 = 0, Ua3 = 0, hsa = 0;
#pragma unroll
    for (int n = 0; n < 3; ++n) {
      float f0 = r[10 + 2 * n], f1 = r[11 + 2 * n];
      float f2 = r[20 + 2 * n], f3 = r[21 + 2 * n];
      float t = fmaf(f0, w1a0, fmaf(f1, w1a1, fmaf(f2, w1a2, fmaf(f3, w1a3, vb1a))));
      float h = t > 0.f ? t : 0.01f * t;
      Ua0 = fmaf(h, f0, Ua0); Ua1 = fmaf(h, f1, Ua1);
      Ua2 = fmaf(h, f2, Ua2); Ua3 = fmaf(h, f3, Ua3); hsa += h;
    }
    {
      auto p0 = __builtin_amdgcn_cvt_pkrtz(Ua0, Ua1);
      auto p1 = __builtin_amdgcn_cvt_pkrtz(Ua2, Ua3);
      *(decltype(p0)*)(fr + 4 * lane) = p0;        // merged -> ds_write_b64
      *(decltype(p1)*)(fr + 4 * lane + 2) = p1;
      fr[256 + lane] = (_Float16)hsa;
    }

    // adv (2 entities, d=4)
    float Ud0 = 0, Ud1 = 0, Ud2 = 0, Ud3 = 0, hsd = 0;
#pragma unroll
    for (int n = 0; n < 2; ++n) {
      float f0 = r[16 + 2 * n], f1 = r[17 + 2 * n];
      float f2 = r[26 + 2 * n], f3 = r[27 + 2 * n];
      float t = fmaf(f0, w1d0, fmaf(f1, w1d1, fmaf(f2, w1d2, fmaf(f3, w1d3, vb1d))));
      float h = t > 0.f ? t : 0.01f * t;
      Ud0 = fmaf(h, f0, Ud0); Ud1 = fmaf(h, f1, Ud1);
      Ud2 = fmaf(h, f2, Ud2); Ud3 = fmaf(h, f3, Ud3); hsd += h;
    }
    {
      auto p0 = __builtin_amdgcn_cvt_pkrtz(Ud0, Ud1);
      auto p1 = __builtin_amdgcn_cvt_pkrtz(Ud2, Ud3);
      *(decltype(p0)*)(fr + 324 + 4 * lane) = p0;
      *(decltype(p1)*)(fr + 324 + 4 * lane + 2) = p1;
      fr[580 + lane] = (_Float16)hsd;
    }

    // landmarks (3 entities, d=2)
    float Ul0 = 0, Ul1 = 0, hsl = 0;
#pragma unroll
    for (int n = 0; n < 3; ++n) {
      float f0 = r[4 + 2 * n], f1 = r[5 + 2 * n];
      float t = fmaf(f0, w1l0, fmaf(f1, w1l1, vb1l));
      float h = t > 0.f ? t : 0.01f * t;
      Ul0 = fmaf(h, f0, Ul0); Ul1 = fmaf(h, f1, Ul1); hsl += h;
    }
    {
      auto pl = __builtin_amdgcn_cvt_pkrtz(Ul0, Ul1);
      *(decltype(pl)*)(fr + 648 + 2 * lane) = pl;
      fr[776 + lane] = (_Float16)hsl;
    }
  }

  // ---- specials pass: this wave's 8 samples x 16 slots over 2 x 64 lanes ----
#pragma unroll
  for (int p = 0; p < 2; ++p) {
    int idx = p * 64 + lane;
    int i = wave * 8 + (idx >> 4), t = idx & 15;
    const float* rs = stage + i * 32;
    float val;
    if (t < 4)       { int b = ((t < 2) ? 10 : 20) + (t & 1); val = rs[b] + rs[b + 2] + rs[b + 4]; }
    else if (t < 8)  { int b = ((t < 6) ? 16 : 26) + (t & 1); val = rs[b] + rs[b + 2]; }
    else if (t < 10) { int b = 4 + (t & 1);                   val = rs[b] + rs[b + 2] + rs[b + 4]; }
    else if (t < 14) {                                        val = rs[t - 10]; }
    else if (t == 14){                                        val = 1.0f; }
    else             {                                        val = 0.0f; }
    int k = (t < 4) ? 320 + t : (t < 8) ? 640 + t : (t < 15) ? 832 + t : 863;
    feats[i * FSTRIDE + k] = (_Float16)val;
  }

  __syncthreads();   // all 16 feature rows complete

  // ---- Phase 2: K-split GEMM, D(16x64) = F(16x864) @ M(864x64) ----
  f32x4 acc[4];
#pragma unroll
  for (int nt = 0; nt < 4; ++nt) acc[nt] = (f32x4){0.f, 0.f, 0.f, 0.f};

  const _Float16* aptr = feats + m * FSTRIDE + quad * 8;
  {
    f16x8 af = *(const f16x8*)(aptr + kk0 * 32);
#pragma unroll
    for (int nt = 0; nt < 4; ++nt)
      acc[nt] = __builtin_amdgcn_mfma_f32_16x16x32_f16(af, bp[nt], acc[nt], 0, 0, 0);
  }
  const int kkend = kk0 + 13 + wave;   // wave0: 13 tiles, wave1: 14
#pragma unroll 3
  for (int kk = kk0 + 1; kk < kkend; ++kk) {
    f16x8 af = *(const f16x8*)(aptr + kk * 32);
#pragma unroll
    for (int nt = 0; nt < 4; ++nt) {
      f16x8 bf = *(const f16x8*)(bbase + (kk * 4 + nt) * 512);
      acc[nt] = __builtin_amdgcn_mfma_f32_16x16x32_f16(af, bf, acc[nt], 0, 0, 0);
    }
  }

  // ---- combine partials: wave1 -> LDS, wave0 accumulates ----
  if (wave == 1) {
#pragma unroll
    for (int nt = 0; nt < 4; ++nt)
#pragma unroll
      for (int i = 0; i < 4; ++i)
        partial[(nt * 4 + i) * 64 + lane] = acc[nt][i];
  }
  __syncthreads();
  if (wave == 1) return;
#pragma unroll
  for (int nt = 0; nt < 4; ++nt)
#pragma unroll
    for (int i = 0; i < 4; ++i)
      acc[nt][i] += partial[(nt * 4 + i) * 64 + lane];

  // fc1 B fragments: issue now so the loads overlap the outact writes below
  const _Float16* cbase = fc1B + lane * 8;
  f16x8 cfrag[12];
#pragma unroll
  for (int t = 0; t < 12; ++t) cfrag[t] = *(const f16x8*)(cbase + t * 512);

  // ---- Epilogue (wave0): relu(acc) -> LDS f16, append actions + 1 ----
#pragma unroll
  for (int nt = 0; nt < 4; ++nt)
#pragma unroll
    for (int i = 0; i < 4; ++i) {
      int rrow = quad * 4 + i;
      float v = fmaxf(acc[nt][i], 0.f);
      outact[rrow * OSTRIDE + nt * 16 + m] = (_Float16)v;
    }
  if (lane < 16) {
    _Float16* orp = outact + lane * OSTRIDE;
    orp[64] = (_Float16)a0;
    orp[65] = (_Float16)a1;
    orp[66] = (_Float16)1.0f;
  }

  // ---- fc1: X(16x64) = relu( OA(16x96) @ fc1B^T ) ----
  f32x4 xacc[4];
#pragma unroll
  for (int nt = 0; nt < 4; ++nt) xacc[nt] = (f32x4){0.f, 0.f, 0.f, 0.f};
  const _Float16* aptr2 = outact + m * OSTRIDE + quad * 8;
#pragma unroll
  for (int kk = 0; kk < 3; ++kk) {
    f16x8 af = *(const f16x8*)(aptr2 + kk * 32);
#pragma unroll
    for (int nt = 0; nt < 4; ++nt)
      xacc[nt] = __builtin_amdgcn_mfma_f32_16x16x32_f16(af, cfrag[kk * 4 + nt], xacc[nt], 0, 0, 0);
  }

  // ---- store x, fc2 reduce -> q ----
#pragma unroll
  for (int i = 0; i < 4; ++i) {
    int rrow = quad * 4 + i;
    int s = base + rrow;
    float x0 = fmaxf(xacc[0][i], 0.f);
    float x1 = fmaxf(xacc[1][i], 0.f);
    float x2 = fmaxf(xacc[2][i], 0.f);
    float x3 = fmaxf(xacc[3][i], 0.f);
    x_out[s * 64 + m]      = x0;   // 16 lanes -> one aligned 64B segment
    x_out[s * 64 + 16 + m] = x1;
    x_out[s * 64 + 32 + m] = x2;
    x_out[s * 64 + 48 + m] = x3;
    float p = fmaf(x0, wq0, fmaf(x1, wq1, fmaf(x2, wq2, x3 * wq3)));
    p += __shfl_xor(p, 1, 64);
    p += __shfl_xor(p, 2, 64);
    p += __shfl_xor(p, 4, 64);
    p += __shfl_xor(p, 8, 64);
    if (m == 0) q_out[s] = p + qb;
  }
}

extern "C" void kernel_launch(void* const* d_in, const int* in_sizes, int n_in,
                              void* d_out, int out_size, void* d_ws, size_t ws_size,
                              hipStream_t stream) {
  const float* inputs  = (const float*)d_in[0];
  // d_in[1] = hidden_state (unused by the reference)
  const float* actions = (const float*)d_in[2];
  const float* selfW   = (const float*)d_in[3];
  const float* selfB   = (const float*)d_in[4];
  const float* W1a = (const float*)d_in[5],  *B1a = (const float*)d_in[6];
  const float* W2a = (const float*)d_in[7],  *b2a = (const float*)d_in[8];
  const float* W1d = (const float*)d_in[9],  *B1d = (const float*)d_in[10];
  const float* W2d = (const float*)d_in[11], *b2d = (const float*)d_in[12];
  const float* W1l = (const float*)d_in[13], *B1l = (const float*)d_in[14];
  const float* W2l = (const float*)d_in[15], *b2l = (const float*)d_in[16];
  const float* mergerW = (const float*)d_in[17];
  const float* fc1W = (const float*)d_in[18], *fc1b = (const float*)d_in[19];
  const float* fc2W = (const float*)d_in[20], *fc2b = (const float*)d_in[21];

  _Float16* matB = (_Float16*)d_ws;             // 64*864 f16, fragment order
  _Float16* fc1B = matB + 64 * KTOT;            // 64*96 f16, fragment order

  const int n = in_sizes[0] / 30;               // 16384
  precompute_kernel<<<240, 256, 0, stream>>>(selfW, selfB, W2a, b2a, W2d, b2d,
                                             W2l, b2l, mergerW, fc1W, fc1b,
                                             matB, fc1B);
  float* q_out = (float*)d_out;
  float* x_out = q_out + n;
  hpn_main<<<n / 16, 128, 0, stream>>>(inputs, actions, W1a, B1a, W1d, B1d,
                                       W1l, B1l, matB, fc1B, fc2W, fc2b,
                                       q_out, x_out);
}

// Round 5
// 107.191 us; speedup vs baseline: 1.2586x; 1.0180x over previous
//
#include <hip/hip_runtime.h>

typedef __attribute__((ext_vector_type(8))) _Float16 f16x8;
typedef __attribute__((ext_vector_type(4))) float f32x4;

#define KTOT 864      // padded K (847 used, zero-padded to 27*32)
#define FSTRIDE 872   // f16 elems per feature row in LDS (multiple of 8)
#define OSTRIDE 104   // f16 elems per out_act row in LDS (96 used)

// ---------------------------------------------------------------------------
// Precompute: fold softmax(merger_w) head-weights into W2/b2. Output is in
// MFMA *fragment order*: matB[((kk*4+nt)*64 + lane)*8 + j] holds the f16
// element (c = nt*16 + (lane&15), k = kk*32 + (lane>>4)*8 + j). Same for fc1B.
// Logical (c,k) map (j-major U packing so the main kernel's feature writes
// are contiguous per lane):
//   ally : U k=4j+kk (0..255), hsum 256..319, fsum 320..323
//   adv  : base 324: U 324+4j+kk (..579), hsum 580..643, fsum 644..647
//   lm   : base 648: U 648+2j+kk (..775), hsum 776..839, fsum 840..841
//   self : 842..845, const-1 (all biases) : 846, zero pad 847..863
// ---------------------------------------------------------------------------
__global__ __launch_bounds__(256) void precompute_kernel(
    const float* __restrict__ selfW, const float* __restrict__ selfB,
    const float* __restrict__ W2a, const float* __restrict__ b2a,
    const float* __restrict__ W2d, const float* __restrict__ b2d,
    const float* __restrict__ W2l, const float* __restrict__ b2l,
    const float* __restrict__ mergerW,
    const float* __restrict__ fc1W, const float* __restrict__ fc1b,
    _Float16* __restrict__ matB, _Float16* __restrict__ fc1B)
{
  int g = blockIdx.x * 256 + threadIdx.x;
  if (g < 64 * KTOT) {
    // fragment-order decode
    int j8 = g & 7;
    int l  = (g >> 3) & 63;
    int t  = g >> 9;            // 0..107 = kk*4+nt
    int nt = t & 3, kk = t >> 2;
    int c  = nt * 16 + (l & 15);
    int k  = kk * 32 + (l >> 4) * 8 + j8;

    // softmax over the 4 heads for channel c
    float v0 = mergerW[c], v1 = mergerW[64 + c], v2 = mergerW[128 + c], v3 = mergerW[192 + c];
    float mx = fmaxf(fmaxf(v0, v1), fmaxf(v2, v3));
    float e0 = expf(v0 - mx), e1 = expf(v1 - mx), e2 = expf(v2 - mx), e3 = expf(v3 - mx);
    float inv = 1.f / (e0 + e1 + e2 + e3);
    float w0 = e0 * inv, w1 = e1 * inv, w2 = e2 * inv, w3 = e3 * inv;
    auto HS = [&](const float* __restrict__ p, int base) -> float {
      return w0 * p[base + c] + w1 * p[base + 64 + c] + w2 * p[base + 128 + c] + w3 * p[base + 192 + c];
    };
    float val = 0.f;
    if (k < 256)      { int j = k >> 2, kkk = k & 3;              val = HS(W2a, j * 1280 + kkk * 256); }
    else if (k < 320) { int j = k - 256;                          val = HS(W2a, j * 1280 + 1024); }
    else if (k < 324) { int kkk = k - 320;                        val = HS(b2a, kkk * 256); }
    else if (k < 580) { int k2 = k - 324; int j = k2 >> 2, kkk = k2 & 3; val = HS(W2d, j * 1280 + kkk * 256); }
    else if (k < 644) { int j = k - 580;                          val = HS(W2d, j * 1280 + 1024); }
    else if (k < 648) { int kkk = k - 644;                        val = HS(b2d, kkk * 256); }
    else if (k < 776) { int k2 = k - 648; int j = k2 >> 1, kkk = k2 & 1; val = HS(W2l, j * 768 + kkk * 256); }
    else if (k < 840) { int j = k - 776;                          val = HS(W2l, j * 768 + 512); }
    else if (k < 842) { int kkk = k - 840;                        val = HS(b2l, kkk * 256); }
    else if (k < 846) {                                           val = selfW[(k - 842) * 64 + c]; }
    else if (k == 846){ val = 3.f * HS(b2a, 1024) + 2.f * HS(b2d, 1024) + 3.f * HS(b2l, 512) + selfB[c]; }
    matB[g] = (_Float16)val;
  } else {
    int g2 = g - 64 * KTOT;     // < 64*96, grid sized exactly
    int j8 = g2 & 7;
    int l  = (g2 >> 3) & 63;
    int t  = g2 >> 9;           // 0..11 = kk*4+nt
    int nt = t & 3, kk = t >> 2;
    int c  = nt * 16 + (l & 15);
    int k  = kk * 32 + (l >> 4) * 8 + j8;   // 0..95
    float val = 0.f;
    if (k < 66)       val = fc1W[k * 64 + c];   // k=64,65 are the action columns
    else if (k == 66) val = fc1b[c];            // bias via constant-1 feature
    fc1B[g2] = (_Float16)val;
  }
}

// ---------------------------------------------------------------------------
// Main kernel: 4 waves per block, 32 samples per block (2 M-tiles x K-split 4).
//  - wave w builds features for samples 8w..8w+7 (wave-private LDS writes),
//  - barrier,
//  - wave w runs MFMA over K-tiles [7w, 7w+cnt) for BOTH M-tiles (each B
//    fragment reused twice -> half the L2 B-traffic of 16-sample blocks),
//  - barrier, all waves dump f32 partials into the (now dead) feats region,
//  - barrier, waves 2,3 exit; wave t (0/1) combines partials for M-tile t and
//    runs its epilogue (relu -> fc1 MFMA -> relu -> store x, fc2 reduce -> q).
// LDS: feats 55.8KB + 6.7KB stage/outact union = 62.5KB -> 2 blocks/CU,
// 8 waves/CU = 2 waves/SIMD. All DS traffic stride-1 (conflict-free).
// ---------------------------------------------------------------------------
__global__ __launch_bounds__(256) void hpn_main(
    const float* __restrict__ inputs, const float* __restrict__ actions,
    const float* __restrict__ W1a, const float* __restrict__ B1a,
    const float* __restrict__ W1d, const float* __restrict__ B1d,
    const float* __restrict__ W1l, const float* __restrict__ B1l,
    const _Float16* __restrict__ matB, const _Float16* __restrict__ fc1B,
    const float* __restrict__ fc2W, const float* __restrict__ fc2b,
    float* __restrict__ q_out, float* __restrict__ x_out)
{
  __shared__ __align__(16) _Float16 feats[32 * FSTRIDE];   // 55,808 B; partials alias post-MFMA
  __shared__ __align__(16) char     regionB[32 * OSTRIDE * 2]; // 6656 B: stage (pre-barrier) / outact (post)

  float*    stage  = (float*)regionB;        // 32 rows x 32 cols used pre-barrier (4 KB)
  _Float16* outact = (_Float16*)regionB;     // 32 rows x OSTRIDE used post-barrier
  float*    partial = (float*)feats;         // [w][mt][reg][lane] f32, 32 KB, post-MFMA

  const int tid  = threadIdx.x;
  const int lane = tid & 63;
  const int wave = tid >> 6;
  const int base = blockIdx.x * 32;
  const int m = lane & 15;      // MFMA: A row (sample) / B,D col (channel)
  const int quad = lane >> 4;   // MFMA k-subgroup

  // ---- issue long-latency loads up front ----
  float sbuf[4];
#pragma unroll
  for (int c = 0; c < 4; ++c) {      // each wave stages its OWN 8 samples
    int idx = lane + c * 64;         // 0..255
    int row = wave * 8 + (idx >> 5), col = idx & 31;
    sbuf[c] = (col < 30) ? inputs[(base + row) * 30 + col] : 0.f;
  }
  float a0 = 0.f, a1 = 0.f;
  if (wave < 2 && lane < 16) {       // wave t owns M-tile t's epilogue
    int s = base + wave * 16 + lane;
    a0 = actions[2 * s]; a1 = actions[2 * s + 1];
  }

  float w1a0 = W1a[lane], w1a1 = W1a[64 + lane], w1a2 = W1a[128 + lane], w1a3 = W1a[192 + lane];
  float vb1a = B1a[lane];
  float w1d0 = W1d[lane], w1d1 = W1d[64 + lane], w1d2 = W1d[128 + lane], w1d3 = W1d[192 + lane];
  float vb1d = B1d[lane];
  float w1l0 = W1l[lane], w1l1 = W1l[64 + lane];
  float vb1l = B1l[lane];

  float wq0 = fc2W[m], wq1 = fc2W[16 + m], wq2 = fc2W[32 + m], wq3 = fc2W[48 + m];
  float qb = fc2b[0];

  const _Float16* bbase = matB + lane * 8;       // fragment-ordered: 1KB/instr
  const int kk0 = wave * 7;                      // tiles: 7,7,7,6
  const int cnt = (wave == 3) ? 6 : 7;
  f16x8 bp[4];
#pragma unroll
  for (int nt = 0; nt < 4; ++nt) bp[nt] = *(const f16x8*)(bbase + (kk0 * 4 + nt) * 512);

  // ---- stage inputs to LDS (own rows); zero feats pad cols (own rows) ----
#pragma unroll
  for (int c = 0; c < 4; ++c) {
    int idx = lane + c * 64;
    int row = wave * 8 + (idx >> 5), col = idx & 31;
    stage[row * 32 + col] = sbuf[c];
  }
#pragma unroll
  for (int p = 0; p < 2; ++p) {          // feats cols 832..863 := 0 (own 8 rows)
    int idx = p * 64 + lane;             // 0..127 -> 8 rows x 16 dwords
    int row = wave * 8 + (idx >> 4), d = idx & 15;
    *(float*)(feats + row * FSTRIDE + 832 + d * 2) = 0.f;
  }

  // ---- Phase 1: entity features for this wave's 8 samples ----
  for (int ii = 0; ii < 8; ++ii) {
    int i = wave * 8 + ii;
    float r[30];
#pragma unroll
    for (int e = 0; e < 30; ++e) r[e] = stage[i * 32 + e];  // ds_read_b128 merges
    _Float16* fr = feats + i * FSTRIDE;

    // ally (3 entities, d=4)
    float Ua0 = 0, Ua1 = 0, Ua2 = 0, Ua3 = 0, hsa = 0;
#pragma unroll
    for (int n = 0; n < 3; ++n) {
      float f0 = r[10 + 2 * n], f1 = r[11 + 2 * n];
      float f2 = r[20 + 2 * n], f3 = r[21 + 2 * n];
      float t = fmaf(f0, w1a0, fmaf(f1, w1a1, fmaf(f2, w1a2, fmaf(f3, w1a3, vb1a))));
      float h = t > 0.f ? t : 0.01f * t;
      Ua0 = fmaf(h, f0, Ua0); Ua1 = fmaf(h, f1, Ua1);
      Ua2 = fmaf(h, f2, Ua2); Ua3 = fmaf(h, f3, Ua3); hsa += h;
    }
    {
      auto p0 = __builtin_amdgcn_cvt_pkrtz(Ua0, Ua1);
      auto p1 = __builtin_amdgcn_cvt_pkrtz(Ua2, Ua3);
      *(decltype(p0)*)(fr + 4 * lane) = p0;        // merged -> ds_write_b64
      *(decltype(p1)*)(fr + 4 * lane + 2) = p1;
      fr[256 + lane] = (_Float16)hsa;
    }

    // adv (2 entities, d=4)
    float Ud0 = 0, Ud1 = 0, Ud2 = 0, Ud3 = 0, hsd = 0;
#pragma unroll
    for (int n = 0; n < 2; ++n) {
      float f0 = r[16 + 2 * n], f1 = r[17 + 2 * n];
      float f2 = r[26 + 2 * n], f3 = r[27 + 2 * n];
      float t = fmaf(f0, w1d0, fmaf(f1, w1d1, fmaf(f2, w1d2, fmaf(f3, w1d3, vb1d))));
      float h = t > 0.f ? t : 0.01f * t;
      Ud0 = fmaf(h, f0, Ud0); Ud1 = fmaf(h, f1, Ud1);
      Ud2 = fmaf(h, f2, Ud2); Ud3 = fmaf(h, f3, Ud3); hsd += h;
    }
    {
      auto p0 = __builtin_amdgcn_cvt_pkrtz(Ud0, Ud1);
      auto p1 = __builtin_amdgcn_cvt_pkrtz(Ud2, Ud3);
      *(decltype(p0)*)(fr + 324 + 4 * lane) = p0;
      *(decltype(p1)*)(fr + 324 + 4 * lane + 2) = p1;
      fr[580 + lane] = (_Float16)hsd;
    }

    // landmarks (3 entities, d=2)
    float Ul0 = 0, Ul1 = 0, hsl = 0;
#pragma unroll
    for (int n = 0; n < 3; ++n) {
      float f0 = r[4 + 2 * n], f1 = r[5 + 2 * n];
      float t = fmaf(f0, w1l0, fmaf(f1, w1l1, vb1l));
      float h = t > 0.f ? t : 0.01f * t;
      Ul0 = fmaf(h, f0, Ul0); Ul1 = fmaf(h, f1, Ul1); hsl += h;
    }
    {
      auto pl = __builtin_amdgcn_cvt_pkrtz(Ul0, Ul1);
      *(decltype(pl)*)(fr + 648 + 2 * lane) = pl;
      fr[776 + lane] = (_Float16)hsl;
    }
  }

  // ---- specials pass: this wave's 8 samples x 16 slots over 2 x 64 lanes ----
#pragma unroll
  for (int p = 0; p < 2; ++p) {
    int idx = p * 64 + lane;
    int i = wave * 8 + (idx >> 4), t = idx & 15;
    const float* rs = stage + i * 32;
    float val;
    if (t < 4)       { int b = ((t < 2) ? 10 : 20) + (t & 1); val = rs[b] + rs[b + 2] + rs[b + 4]; }
    else if (t < 8)  { int b = ((t < 6) ? 16 : 26) + (t & 1); val = rs[b] + rs[b + 2]; }
    else if (t < 10) { int b = 4 + (t & 1);                   val = rs[b] + rs[b + 2] + rs[b + 4]; }
    else if (t < 14) {                                        val = rs[t - 10]; }
    else if (t == 14){                                        val = 1.0f; }
    else             {                                        val = 0.0f; }
    int k = (t < 4) ? 320 + t : (t < 8) ? 640 + t : (t < 15) ? 832 + t : 863;
    feats[i * FSTRIDE + k] = (_Float16)val;
  }

  __syncthreads();   // all 32 feature rows complete

  // ---- Phase 2: K-split GEMM over 2 M-tiles (B fragment reused twice) ----
  f32x4 acc0[4], acc1[4];
#pragma unroll
  for (int nt = 0; nt < 4; ++nt) { acc0[nt] = (f32x4){0,0,0,0}; acc1[nt] = (f32x4){0,0,0,0}; }

  const _Float16* aptr0 = feats + m * FSTRIDE + quad * 8;
  const _Float16* aptr1 = feats + (16 + m) * FSTRIDE + quad * 8;
  {
    f16x8 af0 = *(const f16x8*)(aptr0 + kk0 * 32);
    f16x8 af1 = *(const f16x8*)(aptr1 + kk0 * 32);
#pragma unroll
    for (int nt = 0; nt < 4; ++nt) {
      acc0[nt] = __builtin_amdgcn_mfma_f32_16x16x32_f16(af0, bp[nt], acc0[nt], 0, 0, 0);
      acc1[nt] = __builtin_amdgcn_mfma_f32_16x16x32_f16(af1, bp[nt], acc1[nt], 0, 0, 0);
    }
  }
#pragma unroll 3
  for (int kk = kk0 + 1; kk < kk0 + cnt; ++kk) {
    f16x8 af0 = *(const f16x8*)(aptr0 + kk * 32);
    f16x8 af1 = *(const f16x8*)(aptr1 + kk * 32);
#pragma unroll
    for (int nt = 0; nt < 4; ++nt) {
      f16x8 bf = *(const f16x8*)(bbase + (kk * 4 + nt) * 512);
      acc0[nt] = __builtin_amdgcn_mfma_f32_16x16x32_f16(af0, bf, acc0[nt], 0, 0, 0);
      acc1[nt] = __builtin_amdgcn_mfma_f32_16x16x32_f16(af1, bf, acc1[nt], 0, 0, 0);
    }
  }

  __syncthreads();   // all feats reads done; safe to overwrite with partials

  // ---- dump partials: [w][mt][reg][lane], stride-1 across lanes ----
#pragma unroll
  for (int nt = 0; nt < 4; ++nt)
#pragma unroll
    for (int i = 0; i < 4; ++i) {
      partial[((wave * 2 + 0) * 16 + nt * 4 + i) * 64 + lane] = acc0[nt][i];
      partial[((wave * 2 + 1) * 16 + nt * 4 + i) * 64 + lane] = acc1[nt][i];
    }
  __syncthreads();
  if (wave >= 2) return;

  // fc1 B fragments: issue early so global latency overlaps the DS combine
  const _Float16* cbase = fc1B + lane * 8;
  f16x8 cfrag[12];
#pragma unroll
  for (int t = 0; t < 12; ++t) cfrag[t] = *(const f16x8*)(cbase + t * 512);

  // ---- combine: wave t sums the 4 waves' partials for M-tile t ----
  float facc[16];
#pragma unroll
  for (int g = 0; g < 16; ++g) {
    facc[g] = partial[((0 * 2 + wave) * 16 + g) * 64 + lane]
            + partial[((1 * 2 + wave) * 16 + g) * 64 + lane]
            + partial[((2 * 2 + wave) * 16 + g) * 64 + lane]
            + partial[((3 * 2 + wave) * 16 + g) * 64 + lane];
  }

  // ---- epilogue (wave t, M-tile t): relu -> outact f16, append actions+1 ----
  const int rbase = wave * 16;
#pragma unroll
  for (int p = 0; p < 4; ++p) {          // zero own 16 rows' cols 64..95
    int idx = p * 64 + lane;             // 0..255 -> 16 rows x 16 dwords
    int row = rbase + (idx >> 4), d = idx & 15;
    *(float*)(outact + row * OSTRIDE + 64 + d * 2) = 0.f;
  }
#pragma unroll
  for (int nt = 0; nt < 4; ++nt)
#pragma unroll
    for (int i = 0; i < 4; ++i) {
      int rrow = rbase + quad * 4 + i;
      float v = fmaxf(facc[nt * 4 + i], 0.f);
      outact[rrow * OSTRIDE + nt * 16 + m] = (_Float16)v;
    }
  if (lane < 16) {
    _Float16* orp = outact + (rbase + lane) * OSTRIDE;
    orp[64] = (_Float16)a0;
    orp[65] = (_Float16)a1;
    orp[66] = (_Float16)1.0f;
  }

  // ---- fc1: X(16x64) = relu( OA(16x96) @ fc1B^T ) ----
  f32x4 xacc[4];
#pragma unroll
  for (int nt = 0; nt < 4; ++nt) xacc[nt] = (f32x4){0,0,0,0};
  const _Float16* aptr2 = outact + (rbase + m) * OSTRIDE + quad * 8;
#pragma unroll
  for (int kk = 0; kk < 3; ++kk) {
    f16x8 af = *(const f16x8*)(aptr2 + kk * 32);
#pragma unroll
    for (int nt = 0; nt < 4; ++nt)
      xacc[nt] = __builtin_amdgcn_mfma_f32_16x16x32_f16(af, cfrag[kk * 4 + nt], xacc[nt], 0, 0, 0);
  }

  // ---- store x, fc2 reduce -> q ----
#pragma unroll
  for (int i = 0; i < 4; ++i) {
    int s = base + rbase + quad * 4 + i;
    float x0 = fmaxf(xacc[0][i], 0.f);
    float x1 = fmaxf(xacc[1][i], 0.f);
    float x2 = fmaxf(xacc[2][i], 0.f);
    float x3 = fmaxf(xacc[3][i], 0.f);
    x_out[s * 64 + m]      = x0;   // 16 lanes -> one aligned 64B segment
    x_out[s * 64 + 16 + m] = x1;
    x_out[s * 64 + 32 + m] = x2;
    x_out[s * 64 + 48 + m] = x3;
    float p = fmaf(x0, wq0, fmaf(x1, wq1, fmaf(x2, wq2, x3 * wq3)));
    p += __shfl_xor(p, 1, 64);
    p += __shfl_xor(p, 2, 64);
    p += __shfl_xor(p, 4, 64);
    p += __shfl_xor(p, 8, 64);
    if (m == 0) q_out[s] = p + qb;
  }
}

extern "C" void kernel_launch(void* const* d_in, const int* in_sizes, int n_in,
                              void* d_out, int out_size, void* d_ws, size_t ws_size,
                              hipStream_t stream) {
  const float* inputs  = (const float*)d_in[0];
  // d_in[1] = hidden_state (unused by the reference)
  const float* actions = (const float*)d_in[2];
  const float* selfW   = (const float*)d_in[3];
  const float* selfB   = (const float*)d_in[4];
  const float* W1a = (const float*)d_in[5],  *B1a = (const float*)d_in[6];
  const float* W2a = (const float*)d_in[7],  *b2a = (const float*)d_in[8];
  const float* W1d = (const float*)d_in[9],  *B1d = (const float*)d_in[10];
  const float* W2d = (const float*)d_in[11], *b2d = (const float*)d_in[12];
  const float* W1l = (const float*)d_in[13], *B1l = (const float*)d_in[14];
  const float* W2l = (const float*)d_in[15], *b2l = (const float*)d_in[16];
  const float* mergerW = (const float*)d_in[17];
  const float* fc1W = (const float*)d_in[18], *fc1b = (const float*)d_in[19];
  const float* fc2W = (const float*)d_in[20], *fc2b = (const float*)d_in[21];

  _Float16* matB = (_Float16*)d_ws;             // 64*864 f16, fragment order
  _Float16* fc1B = matB + 64 * KTOT;            // 64*96 f16, fragment order

  const int n = in_sizes[0] / 30;               // 16384
  precompute_kernel<<<240, 256, 0, stream>>>(selfW, selfB, W2a, b2a, W2d, b2d,
                                             W2l, b2l, mergerW, fc1W, fc1b,
                                             matB, fc1B);
  float* q_out = (float*)d_out;
  float* x_out = q_out + n;
  hpn_main<<<n / 32, 256, 0, stream>>>(inputs, actions, W1a, B1a, W1d, B1d,
                                       W1l, B1l, matB, fc1B, fc2W, fc2b,
                                       q_out, x_out);
}